// Round 11
// baseline (1552.300 us; speedup 1.0000x reference)
//
#include <hip/hip_runtime.h>
#include <hip/hip_bf16.h>

#define N_NODES 100000
#define D 64
#define SCAN_N (N_NODES + 1)
#define CHUNK 1024
#define NBLK ((SCAN_N + CHUNK - 1) / CHUNK)   // 98

// ---------------- CSR build: histogram -> 2-level exclusive scan -> fill ----

__global__ __launch_bounds__(256) void hist_kernel(
    const int* __restrict__ dst, int* __restrict__ deg, int n_edges)
{
    int i = blockIdx.x * blockDim.x + threadIdx.x;
    if (i < n_edges) atomicAdd(&deg[dst[i]], 1);
}

__global__ __launch_bounds__(CHUNK) void scan_part1(
    const int* __restrict__ deg, int* __restrict__ bsum)
{
    __shared__ int tmp[CHUNK];
    int i = blockIdx.x * CHUNK + threadIdx.x;
    tmp[threadIdx.x] = (i < SCAN_N) ? deg[i] : 0;
    __syncthreads();
    for (int off = CHUNK / 2; off > 0; off >>= 1) {
        if (threadIdx.x < off) tmp[threadIdx.x] += tmp[threadIdx.x + off];
        __syncthreads();
    }
    if (threadIdx.x == 0) bsum[blockIdx.x] = tmp[0];
}

__global__ __launch_bounds__(128) void scan_part2(int* __restrict__ bsum)
{
    __shared__ int tmp[128];
    int v = (threadIdx.x < NBLK) ? bsum[threadIdx.x] : 0;
    tmp[threadIdx.x] = v;
    __syncthreads();
    for (int off = 1; off < 128; off <<= 1) {
        int t = (threadIdx.x >= off) ? tmp[threadIdx.x - off] : 0;
        __syncthreads();
        tmp[threadIdx.x] += t;
        __syncthreads();
    }
    if (threadIdx.x < NBLK) bsum[threadIdx.x] = tmp[threadIdx.x] - v;  // exclusive
}

__global__ __launch_bounds__(CHUNK) void scan_part3(
    const int* __restrict__ deg, const int* __restrict__ bsum,
    int* __restrict__ row_start, int* __restrict__ cursor)
{
    __shared__ int tmp[CHUNK];
    int i = blockIdx.x * CHUNK + threadIdx.x;
    int v = (i < SCAN_N) ? deg[i] : 0;
    tmp[threadIdx.x] = v;
    __syncthreads();
    for (int off = 1; off < CHUNK; off <<= 1) {
        int t = (threadIdx.x >= off) ? tmp[threadIdx.x - off] : 0;
        __syncthreads();
        tmp[threadIdx.x] += t;
        __syncthreads();
    }
    if (i < SCAN_N) {
        int excl = bsum[blockIdx.x] + tmp[threadIdx.x] - v;
        row_start[i] = excl;
        if (i < N_NODES) cursor[i] = excl;
    }
}

__global__ __launch_bounds__(256) void fill_kernel(
    const int* __restrict__ src, const int* __restrict__ dst,
    int* __restrict__ cursor, int* __restrict__ esrc, int n_edges)
{
    int i = blockIdx.x * blockDim.x + threadIdx.x;
    if (i < n_edges) {
        int pos = atomicAdd(&cursor[dst[i]], 1);
        esrc[pos] = src[i];
    }
}

// ---------------- type helpers ----------------------------------------------

__device__ __forceinline__ float4 ld4(const float* p) {
    return *reinterpret_cast<const float4*>(p);
}
__device__ __forceinline__ float4 ld4(const __hip_bfloat16* p) {
    const ushort4 u = *reinterpret_cast<const ushort4*>(p);
    float4 v;
    v.x = __uint_as_float((unsigned)u.x << 16);
    v.y = __uint_as_float((unsigned)u.y << 16);
    v.z = __uint_as_float((unsigned)u.z << 16);
    v.w = __uint_as_float((unsigned)u.w << 16);
    return v;
}
__device__ __forceinline__ void st4(float* p, float4 v) { *reinterpret_cast<float4*>(p) = v; }
__device__ __forceinline__ void st4(__hip_bfloat16* p, float4 v) {
    p[0] = __float2bfloat16(v.x); p[1] = __float2bfloat16(v.y);
    p[2] = __float2bfloat16(v.z); p[3] = __float2bfloat16(v.w);
}
__device__ __forceinline__ void fma4(float4& acc, float s, const float4& w) {
    acc.x += s * w.x; acc.y += s * w.y; acc.z += s * w.z; acc.w += s * w.w;
}

// ---------------- gather: agg[i] = sum_{j->i} xin[j] ------------------------
// One wave per node, no LDS, low VGPR. lane = g*16+c: edge slot g, float4
// chunk c. Full row written -> no memset needed.
template <typename AT>
__global__ __launch_bounds__(256) void gather_kernel(
    const float* __restrict__ xin,
    const int* __restrict__ row_start,
    const int* __restrict__ esrc,
    AT* __restrict__ agg)
{
    const int wid = (blockIdx.x * 256 + threadIdx.x) >> 6;   // node
    if (wid >= N_NODES) return;
    const int lane = threadIdx.x & 63;
    const int g = lane >> 4;      // 0..3 edge slot
    const int c = lane & 15;      // 0..15 float4 chunk

    const int beg = row_start[wid];
    const int end = row_start[wid + 1];

    float4 acc = make_float4(0.f, 0.f, 0.f, 0.f);
    for (int e = beg; e < end; e += 8) {
        const int i0 = e + g;
        const int i1 = e + 4 + g;
        if (i0 < end) {
            const float4 v = *reinterpret_cast<const float4*>(
                &xin[(long)esrc[i0] * D + c * 4]);
            acc.x += v.x; acc.y += v.y; acc.z += v.z; acc.w += v.w;
        }
        if (i1 < end) {
            const float4 v = *reinterpret_cast<const float4*>(
                &xin[(long)esrc[i1] * D + c * 4]);
            acc.x += v.x; acc.y += v.y; acc.z += v.z; acc.w += v.w;
        }
    }
    acc.x += __shfl_xor(acc.x, 16); acc.y += __shfl_xor(acc.y, 16);
    acc.z += __shfl_xor(acc.z, 16); acc.w += __shfl_xor(acc.w, 16);
    acc.x += __shfl_xor(acc.x, 32); acc.y += __shfl_xor(acc.y, 32);
    acc.z += __shfl_xor(acc.z, 32); acc.w += __shfl_xor(acc.w, 32);

    if (g == 0) st4(&agg[(long)wid * D + c * 4], acc);
}

// ---------------- dense: out = [relu]([agg|x] @ [Wrel|Wroot]^T + b) ---------
// Tiled f32 GEMM. Block = 256 threads = 64-node x 64-col tile, K=128 in two
// 64-k halves (agg then x). Thread computes 4 nodes x 4 cols (16 independent
// accumulators). All LDS traffic is ds_read_b128, <=2-way bank aliasing.
// In-place safe (out==xin): each block reads only its own rows before writing.
#define AS 68   // Alds row stride in dwords: (4n+k)%32 -> 2-way max
template <typename AT, int RELU>
__global__ __launch_bounds__(256) void dense_kernel(
    const AT* __restrict__ agg,
    const float* __restrict__ xin,
    const float* __restrict__ Wrel,
    const float* __restrict__ brel,
    const float* __restrict__ Wroot,
    float* __restrict__ out)
{
    __shared__ float Wlds[2][64 * 64];   // [h][k*64+j] = W^T (k-major)
    __shared__ float Alds[64 * AS];

    const int t = threadIdx.x;
    // Stage W transposed. Reads are uncoalesced (stride 256B) but W is 16KB
    // and L2-hot; writes are conflict-free (bank = j%32, j consecutive).
    for (int i = t; i < 4096; i += 256) {
        const int j = i & 63, k = i >> 6;
        Wlds[0][k * 64 + j] = Wrel[j * 64 + k];
        Wlds[1][k * 64 + j] = Wroot[j * 64 + k];
    }

    const int tc = t & 15;        // col group: cols 4tc..4tc+3
    const int tn = t >> 4;        // node group: nodes 4tn..4tn+3
    const int node0 = blockIdx.x * 64;

    const float4 bias = *reinterpret_cast<const float4*>(&brel[tc * 4]);
    float4 acc0 = bias, acc1 = bias, acc2 = bias, acc3 = bias;

#pragma unroll
    for (int half = 0; half < 2; ++half) {
        __syncthreads();   // Alds reuse (also orders W staging on half 0)
        for (int i = t; i < 1024; i += 256) {      // 64 nodes x 16 float4
            const int n = i >> 4, kq = i & 15;
            int gn = node0 + n; if (gn > N_NODES - 1) gn = N_NODES - 1;
            float4 v;
            if (half == 0) v = ld4(&agg[(long)gn * D + kq * 4]);
            else           v = ld4(&xin[(long)gn * D + kq * 4]);
            *reinterpret_cast<float4*>(&Alds[n * AS + kq * 4]) = v;
        }
        __syncthreads();

        const float* W = Wlds[half];
#pragma unroll
        for (int kb = 0; kb < 64; kb += 4) {
            const float4 w0 = *reinterpret_cast<const float4*>(&W[(kb + 0) * 64 + tc * 4]);
            const float4 w1 = *reinterpret_cast<const float4*>(&W[(kb + 1) * 64 + tc * 4]);
            const float4 w2 = *reinterpret_cast<const float4*>(&W[(kb + 2) * 64 + tc * 4]);
            const float4 w3 = *reinterpret_cast<const float4*>(&W[(kb + 3) * 64 + tc * 4]);
            const float4 a0 = *reinterpret_cast<const float4*>(&Alds[(tn * 4 + 0) * AS + kb]);
            const float4 a1 = *reinterpret_cast<const float4*>(&Alds[(tn * 4 + 1) * AS + kb]);
            const float4 a2 = *reinterpret_cast<const float4*>(&Alds[(tn * 4 + 2) * AS + kb]);
            const float4 a3 = *reinterpret_cast<const float4*>(&Alds[(tn * 4 + 3) * AS + kb]);
            fma4(acc0, a0.x, w0); fma4(acc0, a0.y, w1); fma4(acc0, a0.z, w2); fma4(acc0, a0.w, w3);
            fma4(acc1, a1.x, w0); fma4(acc1, a1.y, w1); fma4(acc1, a1.z, w2); fma4(acc1, a1.w, w3);
            fma4(acc2, a2.x, w0); fma4(acc2, a2.y, w1); fma4(acc2, a2.z, w2); fma4(acc2, a2.w, w3);
            fma4(acc3, a3.x, w0); fma4(acc3, a3.y, w1); fma4(acc3, a3.z, w2); fma4(acc3, a3.w, w3);
        }
    }

    float4 r[4] = {acc0, acc1, acc2, acc3};
#pragma unroll
    for (int i = 0; i < 4; ++i) {
        if (RELU) {
            r[i].x = fmaxf(r[i].x, 0.f); r[i].y = fmaxf(r[i].y, 0.f);
            r[i].z = fmaxf(r[i].z, 0.f); r[i].w = fmaxf(r[i].w, 0.f);
        }
        const int gn = node0 + tn * 4 + i;
        if (gn < N_NODES)
            *reinterpret_cast<float4*>(&out[(long)gn * D + tc * 4]) = r[i];
    }
}

// ---------------------------------------------------------------------------

extern "C" void kernel_launch(void* const* d_in, const int* in_sizes, int n_in,
                              void* d_out, int out_size, void* d_ws, size_t ws_size,
                              hipStream_t stream)
{
    const float* x     = (const float*)d_in[0];
    const int*   ei    = (const int*)d_in[1];
    const float* Wrel1 = (const float*)d_in[2];
    const float* brel1 = (const float*)d_in[3];
    const float* Wroot1= (const float*)d_in[4];
    const float* Wrel2 = (const float*)d_in[5];
    const float* brel2 = (const float*)d_in[6];
    const float* Wroot2= (const float*)d_in[7];
    float* out = (float*)d_out;

    const int n_edges = in_sizes[1] / 2;
    const int* src = ei;
    const int* dst = ei + n_edges;

    // workspace layout (ints)
    int* base      = (int*)d_ws;
    int* row_start = base;                       // SCAN_N
    int* deg       = base + 100352;              // SCAN_N
    int* cursor    = base + 200704;              // N_NODES
    int* bsum      = base + 301056;              // 128
    int* esrc      = base + 301184;              // n_edges
    const size_t agg_off = (((size_t)(301184 + n_edges) * 4) + 255) & ~(size_t)255;
    const size_t f32agg_need = agg_off + (size_t)N_NODES * D * 4 + 1024;

    // ---- build CSR (dst-sorted) ----
    hipMemsetAsync(deg, 0, (size_t)SCAN_N * sizeof(int), stream);
    hist_kernel<<<(n_edges + 255) / 256, 256, 0, stream>>>(dst, deg, n_edges);
    scan_part1<<<NBLK, CHUNK, 0, stream>>>(deg, bsum);
    scan_part2<<<1, 128, 0, stream>>>(bsum);
    scan_part3<<<NBLK, CHUNK, 0, stream>>>(deg, bsum, row_start, cursor);
    fill_kernel<<<(n_edges + 255) / 256, 256, 0, stream>>>(src, dst, cursor, esrc, n_edges);

    const int GB = (N_NODES * 64 + 255) / 256;   // gather: wave per node
    const int DB = (N_NODES + 63) / 64;          // dense: tile per block (1563)

    if (ws_size >= f32agg_need) {
        float* agg = (float*)((char*)d_ws + agg_off);
        gather_kernel<float><<<GB, 256, 0, stream>>>(x, row_start, esrc, agg);
        dense_kernel<float, 1><<<DB, 256, 0, stream>>>(agg, x, Wrel1, brel1, Wroot1, out);
        gather_kernel<float><<<GB, 256, 0, stream>>>(out, row_start, esrc, agg);
        dense_kernel<float, 0><<<DB, 256, 0, stream>>>(agg, out, Wrel2, brel2, Wroot2, out);
    } else {
        __hip_bfloat16* agg = (__hip_bfloat16*)((char*)d_ws + agg_off);
        gather_kernel<__hip_bfloat16><<<GB, 256, 0, stream>>>(x, row_start, esrc, agg);
        dense_kernel<__hip_bfloat16, 1><<<DB, 256, 0, stream>>>(agg, x, Wrel1, brel1, Wroot1, out);
        gather_kernel<__hip_bfloat16><<<GB, 256, 0, stream>>>(out, row_start, esrc, agg);
        dense_kernel<__hip_bfloat16, 0><<<DB, 256, 0, stream>>>(agg, out, Wrel2, brel2, Wroot2, out);
    }
}

// Round 12
// 447.799 us; speedup vs baseline: 3.4665x; 3.4665x over previous
//
#include <hip/hip_runtime.h>
#include <hip/hip_bf16.h>

#define N_NODES 100000
#define D 64
#define SCAN_N (N_NODES + 1)
#define CHUNK 1024
#define NBLK ((SCAN_N + CHUNK - 1) / CHUNK)   // 98

// ---------------- CSR build: histogram -> 2-level exclusive scan -> fill ----

__global__ __launch_bounds__(256) void hist_kernel(
    const int* __restrict__ dst, int* __restrict__ deg, int n_edges)
{
    int i = blockIdx.x * blockDim.x + threadIdx.x;
    if (i < n_edges) atomicAdd(&deg[dst[i]], 1);
}

__global__ __launch_bounds__(CHUNK) void scan_part1(
    const int* __restrict__ deg, int* __restrict__ bsum)
{
    __shared__ int tmp[CHUNK];
    int i = blockIdx.x * CHUNK + threadIdx.x;
    tmp[threadIdx.x] = (i < SCAN_N) ? deg[i] : 0;
    __syncthreads();
    for (int off = CHUNK / 2; off > 0; off >>= 1) {
        if (threadIdx.x < off) tmp[threadIdx.x] += tmp[threadIdx.x + off];
        __syncthreads();
    }
    if (threadIdx.x == 0) bsum[blockIdx.x] = tmp[0];
}

__global__ __launch_bounds__(128) void scan_part2(int* __restrict__ bsum)
{
    __shared__ int tmp[128];
    int v = (threadIdx.x < NBLK) ? bsum[threadIdx.x] : 0;
    tmp[threadIdx.x] = v;
    __syncthreads();
    for (int off = 1; off < 128; off <<= 1) {
        int t = (threadIdx.x >= off) ? tmp[threadIdx.x - off] : 0;
        __syncthreads();
        tmp[threadIdx.x] += t;
        __syncthreads();
    }
    if (threadIdx.x < NBLK) bsum[threadIdx.x] = tmp[threadIdx.x] - v;  // exclusive
}

__global__ __launch_bounds__(CHUNK) void scan_part3(
    const int* __restrict__ deg, const int* __restrict__ bsum,
    int* __restrict__ row_start, int* __restrict__ cursor)
{
    __shared__ int tmp[CHUNK];
    int i = blockIdx.x * CHUNK + threadIdx.x;
    int v = (i < SCAN_N) ? deg[i] : 0;
    tmp[threadIdx.x] = v;
    __syncthreads();
    for (int off = 1; off < CHUNK; off <<= 1) {
        int t = (threadIdx.x >= off) ? tmp[threadIdx.x - off] : 0;
        __syncthreads();
        tmp[threadIdx.x] += t;
        __syncthreads();
    }
    if (i < SCAN_N) {
        int excl = bsum[blockIdx.x] + tmp[threadIdx.x] - v;
        row_start[i] = excl;
        if (i < N_NODES) cursor[i] = excl;
    }
}

__global__ __launch_bounds__(256) void fill_kernel(
    const int* __restrict__ src, const int* __restrict__ dst,
    int* __restrict__ cursor, int* __restrict__ esrc, int n_edges)
{
    int i = blockIdx.x * blockDim.x + threadIdx.x;
    if (i < n_edges) {
        int pos = atomicAdd(&cursor[dst[i]], 1);
        esrc[pos] = src[i];
    }
}

// ---------------- type helpers ----------------------------------------------

__device__ __forceinline__ float4 ld4(const float* p) {
    return *reinterpret_cast<const float4*>(p);
}
__device__ __forceinline__ float4 ld4(const __hip_bfloat16* p) {
    const ushort4 u = *reinterpret_cast<const ushort4*>(p);
    float4 v;
    v.x = __uint_as_float((unsigned)u.x << 16);
    v.y = __uint_as_float((unsigned)u.y << 16);
    v.z = __uint_as_float((unsigned)u.z << 16);
    v.w = __uint_as_float((unsigned)u.w << 16);
    return v;
}
__device__ __forceinline__ void st4(float* p, float4 v) { *reinterpret_cast<float4*>(p) = v; }
__device__ __forceinline__ void st4(__hip_bfloat16* p, float4 v) {
    p[0] = __float2bfloat16(v.x); p[1] = __float2bfloat16(v.y);
    p[2] = __float2bfloat16(v.z); p[3] = __float2bfloat16(v.w);
}
__device__ __forceinline__ void fma4(float4& acc, float s, const float4& w) {
    acc.x += s * w.x; acc.y += s * w.y; acc.z += s * w.z; acc.w += s * w.w;
}

// ---------------- gather: agg[i] = sum_{j->i} xin[j] ------------------------

template <typename AT>
__global__ __launch_bounds__(256) void gather_kernel(
    const float* __restrict__ xin,
    const int* __restrict__ row_start,
    const int* __restrict__ esrc,
    AT* __restrict__ agg)
{
    const int wid = (blockIdx.x * 256 + threadIdx.x) >> 6;   // node
    if (wid >= N_NODES) return;
    const int lane = threadIdx.x & 63;
    const int g = lane >> 4;      // 0..3 edge slot
    const int c = lane & 15;      // 0..15 float4 chunk

    const int beg = row_start[wid];
    const int end = row_start[wid + 1];

    float4 acc = make_float4(0.f, 0.f, 0.f, 0.f);
    for (int e = beg; e < end; e += 8) {
        const int i0 = e + g;
        const int i1 = e + 4 + g;
        if (i0 < end) {
            const float4 v = *reinterpret_cast<const float4*>(
                &xin[(long)esrc[i0] * D + c * 4]);
            acc.x += v.x; acc.y += v.y; acc.z += v.z; acc.w += v.w;
        }
        if (i1 < end) {
            const float4 v = *reinterpret_cast<const float4*>(
                &xin[(long)esrc[i1] * D + c * 4]);
            acc.x += v.x; acc.y += v.y; acc.z += v.z; acc.w += v.w;
        }
    }
    acc.x += __shfl_xor(acc.x, 16); acc.y += __shfl_xor(acc.y, 16);
    acc.z += __shfl_xor(acc.z, 16); acc.w += __shfl_xor(acc.w, 16);
    acc.x += __shfl_xor(acc.x, 32); acc.y += __shfl_xor(acc.y, 32);
    acc.z += __shfl_xor(acc.z, 32); acc.w += __shfl_xor(acc.w, 32);

    if (g == 0) st4(&agg[(long)wid * D + c * 4], acc);
}

// ---------------- dense: out = [relu]([agg|x] @ [Wrel|Wroot]^T + b) ---------
// Tiled f32 GEMM, 64-node x 64-col tile per 256-thread block, 4x4 per thread.
// __launch_bounds__(256,4): hard 128-VGPR cap -> pressure-aware scheduling,
// no spills (round-11 spilled at 256 VGPR: 1.7 GB scratch traffic).
// #pragma unroll 4 on kb keeps ~1 iteration of LDS temps live.
#define AS 68   // Alds row stride in dwords
template <typename AT, int RELU>
__global__ __launch_bounds__(256, 4) void dense_kernel(
    const AT* __restrict__ agg,
    const float* __restrict__ xin,
    const float* __restrict__ Wrel,
    const float* __restrict__ brel,
    const float* __restrict__ Wroot,
    float* __restrict__ out)
{
    __shared__ float Wlds[2][64 * 64];   // [h][k*64+j] = W^T (k-major)
    __shared__ float Alds[64 * AS];

    const int t = threadIdx.x;
    for (int i = t; i < 4096; i += 256) {
        const int j = i & 63, k = i >> 6;
        Wlds[0][k * 64 + j] = Wrel[j * 64 + k];
        Wlds[1][k * 64 + j] = Wroot[j * 64 + k];
    }

    const int tc = t & 15;        // col group: cols 4tc..4tc+3
    const int tn = t >> 4;        // node group: nodes 4tn..4tn+3
    const int node0 = blockIdx.x * 64;

    const float4 bias = *reinterpret_cast<const float4*>(&brel[tc * 4]);
    float4 acc0 = bias, acc1 = bias, acc2 = bias, acc3 = bias;

#pragma unroll
    for (int half = 0; half < 2; ++half) {
        __syncthreads();   // Alds reuse (also orders W staging on half 0)
        for (int i = t; i < 1024; i += 256) {      // 64 nodes x 16 float4
            const int n = i >> 4, kq = i & 15;
            int gn = node0 + n; if (gn > N_NODES - 1) gn = N_NODES - 1;
            float4 v;
            if (half == 0) v = ld4(&agg[(long)gn * D + kq * 4]);
            else           v = ld4(&xin[(long)gn * D + kq * 4]);
            *reinterpret_cast<float4*>(&Alds[n * AS + kq * 4]) = v;
        }
        __syncthreads();

        const float* W = Wlds[half];
#pragma unroll 4
        for (int kb = 0; kb < 64; kb += 4) {
            const float4 w0 = *reinterpret_cast<const float4*>(&W[(kb + 0) * 64 + tc * 4]);
            const float4 w1 = *reinterpret_cast<const float4*>(&W[(kb + 1) * 64 + tc * 4]);
            const float4 w2 = *reinterpret_cast<const float4*>(&W[(kb + 2) * 64 + tc * 4]);
            const float4 w3 = *reinterpret_cast<const float4*>(&W[(kb + 3) * 64 + tc * 4]);
            const float4 a0 = *reinterpret_cast<const float4*>(&Alds[(tn * 4 + 0) * AS + kb]);
            const float4 a1 = *reinterpret_cast<const float4*>(&Alds[(tn * 4 + 1) * AS + kb]);
            const float4 a2 = *reinterpret_cast<const float4*>(&Alds[(tn * 4 + 2) * AS + kb]);
            const float4 a3 = *reinterpret_cast<const float4*>(&Alds[(tn * 4 + 3) * AS + kb]);
            fma4(acc0, a0.x, w0); fma4(acc0, a0.y, w1); fma4(acc0, a0.z, w2); fma4(acc0, a0.w, w3);
            fma4(acc1, a1.x, w0); fma4(acc1, a1.y, w1); fma4(acc1, a1.z, w2); fma4(acc1, a1.w, w3);
            fma4(acc2, a2.x, w0); fma4(acc2, a2.y, w1); fma4(acc2, a2.z, w2); fma4(acc2, a2.w, w3);
            fma4(acc3, a3.x, w0); fma4(acc3, a3.y, w1); fma4(acc3, a3.z, w2); fma4(acc3, a3.w, w3);
        }
    }

    float4 r[4] = {acc0, acc1, acc2, acc3};
#pragma unroll
    for (int i = 0; i < 4; ++i) {
        if (RELU) {
            r[i].x = fmaxf(r[i].x, 0.f); r[i].y = fmaxf(r[i].y, 0.f);
            r[i].z = fmaxf(r[i].z, 0.f); r[i].w = fmaxf(r[i].w, 0.f);
        }
        const int gn = node0 + tn * 4 + i;
        if (gn < N_NODES)
            *reinterpret_cast<float4*>(&out[(long)gn * D + tc * 4]) = r[i];
    }
}

// ---------------------------------------------------------------------------

extern "C" void kernel_launch(void* const* d_in, const int* in_sizes, int n_in,
                              void* d_out, int out_size, void* d_ws, size_t ws_size,
                              hipStream_t stream)
{
    const float* x     = (const float*)d_in[0];
    const int*   ei    = (const int*)d_in[1];
    const float* Wrel1 = (const float*)d_in[2];
    const float* brel1 = (const float*)d_in[3];
    const float* Wroot1= (const float*)d_in[4];
    const float* Wrel2 = (const float*)d_in[5];
    const float* brel2 = (const float*)d_in[6];
    const float* Wroot2= (const float*)d_in[7];
    float* out = (float*)d_out;

    const int n_edges = in_sizes[1] / 2;
    const int* src = ei;
    const int* dst = ei + n_edges;

    // workspace layout (ints)
    int* base      = (int*)d_ws;
    int* row_start = base;                       // SCAN_N
    int* deg       = base + 100352;              // SCAN_N
    int* cursor    = base + 200704;              // N_NODES
    int* bsum      = base + 301056;              // 128
    int* esrc      = base + 301184;              // n_edges
    const size_t agg_off = (((size_t)(301184 + n_edges) * 4) + 255) & ~(size_t)255;
    const size_t f32agg_need = agg_off + (size_t)N_NODES * D * 4 + 1024;

    // ---- build CSR (dst-sorted) ----
    hipMemsetAsync(deg, 0, (size_t)SCAN_N * sizeof(int), stream);
    hist_kernel<<<(n_edges + 255) / 256, 256, 0, stream>>>(dst, deg, n_edges);
    scan_part1<<<NBLK, CHUNK, 0, stream>>>(deg, bsum);
    scan_part2<<<1, 128, 0, stream>>>(bsum);
    scan_part3<<<NBLK, CHUNK, 0, stream>>>(deg, bsum, row_start, cursor);
    fill_kernel<<<(n_edges + 255) / 256, 256, 0, stream>>>(src, dst, cursor, esrc, n_edges);

    const int GB = (N_NODES * 64 + 255) / 256;   // gather: wave per node
    const int DB = (N_NODES + 63) / 64;          // dense: tile per block (1563)

    if (ws_size >= f32agg_need) {
        float* agg = (float*)((char*)d_ws + agg_off);
        gather_kernel<float><<<GB, 256, 0, stream>>>(x, row_start, esrc, agg);
        dense_kernel<float, 1><<<DB, 256, 0, stream>>>(agg, x, Wrel1, brel1, Wroot1, out);
        gather_kernel<float><<<GB, 256, 0, stream>>>(out, row_start, esrc, agg);
        dense_kernel<float, 0><<<DB, 256, 0, stream>>>(agg, out, Wrel2, brel2, Wroot2, out);
    } else {
        __hip_bfloat16* agg = (__hip_bfloat16*)((char*)d_ws + agg_off);
        gather_kernel<__hip_bfloat16><<<GB, 256, 0, stream>>>(x, row_start, esrc, agg);
        dense_kernel<__hip_bfloat16, 1><<<DB, 256, 0, stream>>>(agg, x, Wrel1, brel1, Wroot1, out);
        gather_kernel<__hip_bfloat16><<<GB, 256, 0, stream>>>(out, row_start, esrc, agg);
        dense_kernel<__hip_bfloat16, 0><<<DB, 256, 0, stream>>>(agg, out, Wrel2, brel2, Wroot2, out);
    }
}

// Round 13
// 329.483 us; speedup vs baseline: 4.7113x; 1.3591x over previous
//
#include <hip/hip_runtime.h>
#include <hip/hip_bf16.h>

#define N_NODES 100000
#define D 64
#define SCAN_N (N_NODES + 1)
#define NBUCK 256
#define BSH 9                 // bucket = dst >> 9; 256*512 = 131072 >= N_NODES
#define BNODES (1 << BSH)     // 512 nodes per bucket
#define EPB 2048              // edges per block in bucket passes

// ---------------- bucketed CSR build (LDS atomics, XCD-local writes) --------

__global__ __launch_bounds__(256) void bucket_count(
    const int* __restrict__ dst, int* __restrict__ bcount, int n_edges)
{
    __shared__ int lh[NBUCK];
    const int t = threadIdx.x;
    lh[t] = 0;
    __syncthreads();
    const int e0 = blockIdx.x * EPB;
    const int e1 = min(e0 + EPB, n_edges);
    for (int e = e0 + t; e < e1; e += 256)
        atomicAdd(&lh[dst[e] >> BSH], 1);
    __syncthreads();
    if (lh[t]) atomicAdd(&bcount[t], lh[t]);
}

__global__ __launch_bounds__(256) void bucket_scan(
    const int* __restrict__ bcount, int* __restrict__ bstart,
    int* __restrict__ bcursor)
{
    __shared__ int tmp[256];
    const int t = threadIdx.x;
    const int v = bcount[t];
    tmp[t] = v;
    __syncthreads();
    for (int off = 1; off < 256; off <<= 1) {
        const int u = (t >= off) ? tmp[t - off] : 0;
        __syncthreads();
        tmp[t] += u;
        __syncthreads();
    }
    const int excl = tmp[t] - v;
    bstart[t] = excl;
    bcursor[t] = excl;
    if (t == 255) bstart[256] = tmp[255];
}

// scatter packed (src<<9 | dst&511) into per-bucket contiguous regions.
// Per-block bases reserved with ONE atomic per (block,bucket); per-edge
// positions via LDS cursors -> per-block runs are contiguous (write combine).
__global__ __launch_bounds__(256) void bucket_scatter(
    const int* __restrict__ src, const int* __restrict__ dst,
    int* __restrict__ bcursor, unsigned* __restrict__ packed, int n_edges)
{
    __shared__ int lh[NBUCK];
    __shared__ int lb[NBUCK];
    const int t = threadIdx.x;
    lh[t] = 0;
    __syncthreads();
    const int e0 = blockIdx.x * EPB;
    const int e1 = min(e0 + EPB, n_edges);
    for (int e = e0 + t; e < e1; e += 256)
        atomicAdd(&lh[dst[e] >> BSH], 1);
    __syncthreads();
    const int cnt = lh[t];
    lb[t] = cnt ? atomicAdd(&bcursor[t], cnt) : 0;
    __syncthreads();
    lh[t] = lb[t];
    __syncthreads();
    for (int e = e0 + t; e < e1; e += 256) {
        const int d = dst[e];
        const int pos = atomicAdd(&lh[d >> BSH], 1);
        packed[pos] = ((unsigned)src[e] << BSH) | (unsigned)(d & (BNODES - 1));
    }
}

// One block per bucket: LDS hist over 512 local nodes, LDS scan, write
// row_start slice (coalesced) and esrc (scattered only within the block's
// OWN contiguous region -> one XCD, full L2 write combining).
__global__ __launch_bounds__(256) void bucket_csr(
    const unsigned* __restrict__ packed,
    const int* __restrict__ bstart,
    int* __restrict__ row_start,
    int* __restrict__ esrc)
{
    __shared__ int lcnt[BNODES];
    __shared__ int pair[256];
    const int b = blockIdx.x;
    const int t = threadIdx.x;
    const int beg = bstart[b];
    const int end = bstart[b + 1];

    lcnt[t] = 0; lcnt[t + 256] = 0;
    __syncthreads();
    for (int e = beg + t; e < end; e += 256)
        atomicAdd(&lcnt[packed[e] & (BNODES - 1)], 1);
    __syncthreads();

    // 512-wide exclusive scan via 256 pair-scan
    const int v0 = lcnt[2 * t], v1 = lcnt[2 * t + 1];
    pair[t] = v0 + v1;
    __syncthreads();
    for (int off = 1; off < 256; off <<= 1) {
        const int u = (t >= off) ? pair[t - off] : 0;
        __syncthreads();
        pair[t] += u;
        __syncthreads();
    }
    const int pexcl = pair[t] - (v0 + v1);
    __syncthreads();
    lcnt[2 * t]     = pexcl;
    lcnt[2 * t + 1] = pexcl + v0;
    __syncthreads();

    {
        const int l0 = 2 * t, l1 = 2 * t + 1;
        const int n0 = b * BNODES + l0, n1 = b * BNODES + l1;
        if (n0 <= N_NODES) row_start[n0] = beg + lcnt[l0];
        if (n1 <= N_NODES) row_start[n1] = beg + lcnt[l1];
        lcnt[l0] += beg;           // global cursors
        lcnt[l1] += beg;
    }
    __syncthreads();
    for (int e = beg + t; e < end; e += 256) {
        const unsigned p = packed[e];
        const int pos = atomicAdd(&lcnt[p & (BNODES - 1)], 1);
        esrc[pos] = (int)(p >> BSH);
    }
}

// ---------------- type helpers ----------------------------------------------

__device__ __forceinline__ float4 ld4(const float* p) {
    return *reinterpret_cast<const float4*>(p);
}
__device__ __forceinline__ float4 ld4(const __hip_bfloat16* p) {
    const ushort4 u = *reinterpret_cast<const ushort4*>(p);
    float4 v;
    v.x = __uint_as_float((unsigned)u.x << 16);
    v.y = __uint_as_float((unsigned)u.y << 16);
    v.z = __uint_as_float((unsigned)u.z << 16);
    v.w = __uint_as_float((unsigned)u.w << 16);
    return v;
}
__device__ __forceinline__ void st4(float* p, float4 v) { *reinterpret_cast<float4*>(p) = v; }
__device__ __forceinline__ void st4(__hip_bfloat16* p, float4 v) {
    p[0] = __float2bfloat16(v.x); p[1] = __float2bfloat16(v.y);
    p[2] = __float2bfloat16(v.z); p[3] = __float2bfloat16(v.w);
}
__device__ __forceinline__ void fma4(float4& acc, float s, const float4& w) {
    acc.x += s * w.x; acc.y += s * w.y; acc.z += s * w.z; acc.w += s * w.w;
}

// ---------------- gather: agg[i] = sum_{j->i} xin[j] ------------------------

template <typename AT>
__global__ __launch_bounds__(256) void gather_kernel(
    const float* __restrict__ xin,
    const int* __restrict__ row_start,
    const int* __restrict__ esrc,
    AT* __restrict__ agg)
{
    const int wid = (blockIdx.x * 256 + threadIdx.x) >> 6;   // node
    if (wid >= N_NODES) return;
    const int lane = threadIdx.x & 63;
    const int g = lane >> 4;      // 0..3 edge slot
    const int c = lane & 15;      // 0..15 float4 chunk

    const int beg = row_start[wid];
    const int end = row_start[wid + 1];

    float4 acc = make_float4(0.f, 0.f, 0.f, 0.f);
    for (int e = beg; e < end; e += 8) {
        const int i0 = e + g;
        const int i1 = e + 4 + g;
        if (i0 < end) {
            const float4 v = *reinterpret_cast<const float4*>(
                &xin[(long)esrc[i0] * D + c * 4]);
            acc.x += v.x; acc.y += v.y; acc.z += v.z; acc.w += v.w;
        }
        if (i1 < end) {
            const float4 v = *reinterpret_cast<const float4*>(
                &xin[(long)esrc[i1] * D + c * 4]);
            acc.x += v.x; acc.y += v.y; acc.z += v.z; acc.w += v.w;
        }
    }
    acc.x += __shfl_xor(acc.x, 16); acc.y += __shfl_xor(acc.y, 16);
    acc.z += __shfl_xor(acc.z, 16); acc.w += __shfl_xor(acc.w, 16);
    acc.x += __shfl_xor(acc.x, 32); acc.y += __shfl_xor(acc.y, 32);
    acc.z += __shfl_xor(acc.z, 32); acc.w += __shfl_xor(acc.w, 32);

    if (g == 0) st4(&agg[(long)wid * D + c * 4], acc);
}

// ---------------- dense: out = [relu]([agg|x] @ [Wrel|Wroot]^T + b) ---------
// 64x64 tile per 256-thread block, 4x4 per thread. __launch_bounds__(256,4):
// 128-VGPR cap, no spills (round-11 lesson). #pragma unroll 4 on kb.
#define AS 68
template <typename AT, int RELU>
__global__ __launch_bounds__(256, 4) void dense_kernel(
    const AT* __restrict__ agg,
    const float* __restrict__ xin,
    const float* __restrict__ Wrel,
    const float* __restrict__ brel,
    const float* __restrict__ Wroot,
    float* __restrict__ out)
{
    __shared__ float Wlds[2][64 * 64];
    __shared__ float Alds[64 * AS];

    const int t = threadIdx.x;
    for (int i = t; i < 4096; i += 256) {
        const int j = i & 63, k = i >> 6;
        Wlds[0][k * 64 + j] = Wrel[j * 64 + k];
        Wlds[1][k * 64 + j] = Wroot[j * 64 + k];
    }

    const int tc = t & 15;
    const int tn = t >> 4;
    const int node0 = blockIdx.x * 64;

    const float4 bias = *reinterpret_cast<const float4*>(&brel[tc * 4]);
    float4 acc0 = bias, acc1 = bias, acc2 = bias, acc3 = bias;

#pragma unroll
    for (int half = 0; half < 2; ++half) {
        __syncthreads();
        for (int i = t; i < 1024; i += 256) {
            const int n = i >> 4, kq = i & 15;
            int gn = node0 + n; if (gn > N_NODES - 1) gn = N_NODES - 1;
            float4 v;
            if (half == 0) v = ld4(&agg[(long)gn * D + kq * 4]);
            else           v = ld4(&xin[(long)gn * D + kq * 4]);
            *reinterpret_cast<float4*>(&Alds[n * AS + kq * 4]) = v;
        }
        __syncthreads();

        const float* W = Wlds[half];
#pragma unroll 4
        for (int kb = 0; kb < 64; kb += 4) {
            const float4 w0 = *reinterpret_cast<const float4*>(&W[(kb + 0) * 64 + tc * 4]);
            const float4 w1 = *reinterpret_cast<const float4*>(&W[(kb + 1) * 64 + tc * 4]);
            const float4 w2 = *reinterpret_cast<const float4*>(&W[(kb + 2) * 64 + tc * 4]);
            const float4 w3 = *reinterpret_cast<const float4*>(&W[(kb + 3) * 64 + tc * 4]);
            const float4 a0 = *reinterpret_cast<const float4*>(&Alds[(tn * 4 + 0) * AS + kb]);
            const float4 a1 = *reinterpret_cast<const float4*>(&Alds[(tn * 4 + 1) * AS + kb]);
            const float4 a2 = *reinterpret_cast<const float4*>(&Alds[(tn * 4 + 2) * AS + kb]);
            const float4 a3 = *reinterpret_cast<const float4*>(&Alds[(tn * 4 + 3) * AS + kb]);
            fma4(acc0, a0.x, w0); fma4(acc0, a0.y, w1); fma4(acc0, a0.z, w2); fma4(acc0, a0.w, w3);
            fma4(acc1, a1.x, w0); fma4(acc1, a1.y, w1); fma4(acc1, a1.z, w2); fma4(acc1, a1.w, w3);
            fma4(acc2, a2.x, w0); fma4(acc2, a2.y, w1); fma4(acc2, a2.z, w2); fma4(acc2, a2.w, w3);
            fma4(acc3, a3.x, w0); fma4(acc3, a3.y, w1); fma4(acc3, a3.z, w2); fma4(acc3, a3.w, w3);
        }
    }

    float4 r[4] = {acc0, acc1, acc2, acc3};
#pragma unroll
    for (int i = 0; i < 4; ++i) {
        if (RELU) {
            r[i].x = fmaxf(r[i].x, 0.f); r[i].y = fmaxf(r[i].y, 0.f);
            r[i].z = fmaxf(r[i].z, 0.f); r[i].w = fmaxf(r[i].w, 0.f);
        }
        const int gn = node0 + tn * 4 + i;
        if (gn < N_NODES)
            *reinterpret_cast<float4*>(&out[(long)gn * D + tc * 4]) = r[i];
    }
}

// ---------------------------------------------------------------------------

extern "C" void kernel_launch(void* const* d_in, const int* in_sizes, int n_in,
                              void* d_out, int out_size, void* d_ws, size_t ws_size,
                              hipStream_t stream)
{
    const float* x     = (const float*)d_in[0];
    const int*   ei    = (const int*)d_in[1];
    const float* Wrel1 = (const float*)d_in[2];
    const float* brel1 = (const float*)d_in[3];
    const float* Wroot1= (const float*)d_in[4];
    const float* Wrel2 = (const float*)d_in[5];
    const float* brel2 = (const float*)d_in[6];
    const float* Wroot2= (const float*)d_in[7];
    float* out = (float*)d_out;

    const int n_edges = in_sizes[1] / 2;
    const int* src = ei;
    const int* dst = ei + n_edges;

    // workspace layout (ints)
    int* base      = (int*)d_ws;
    int* row_start = base;                       // SCAN_N (padded 100352)
    int* bstart    = base + 100352;              // 257 (padded 320)
    int* bcursor   = base + 100672;              // 256
    int* bcount    = base + 100928;              // 256
    int* esrc      = base + 101184;              // n_edges
    const size_t agg_off = (((size_t)(101184 + n_edges) * 4) + 255) & ~(size_t)255;
    const size_t f32agg_need = agg_off + (size_t)N_NODES * D * 4 + 1024;
    // packed aliases the agg region (consumed by bucket_csr before gather runs)

    const int BB = (n_edges + EPB - 1) / EPB;    // bucket-pass blocks (782)

    hipMemsetAsync(bcount, 0, NBUCK * sizeof(int), stream);
    bucket_count<<<BB, 256, 0, stream>>>(dst, bcount, n_edges);
    bucket_scan<<<1, 256, 0, stream>>>(bcount, bstart, bcursor);

    const int GB = (N_NODES * 64 + 255) / 256;   // gather: wave per node
    const int DB = (N_NODES + 63) / 64;          // dense: tile per block

    if (ws_size >= f32agg_need) {
        float* agg = (float*)((char*)d_ws + agg_off);
        unsigned* packed = (unsigned*)agg;
        bucket_scatter<<<BB, 256, 0, stream>>>(src, dst, bcursor, packed, n_edges);
        bucket_csr<<<NBUCK, 256, 0, stream>>>(packed, bstart, row_start, esrc);

        gather_kernel<float><<<GB, 256, 0, stream>>>(x, row_start, esrc, agg);
        dense_kernel<float, 1><<<DB, 256, 0, stream>>>(agg, x, Wrel1, brel1, Wroot1, out);
        gather_kernel<float><<<GB, 256, 0, stream>>>(out, row_start, esrc, agg);
        dense_kernel<float, 0><<<DB, 256, 0, stream>>>(agg, out, Wrel2, brel2, Wroot2, out);
    } else {
        __hip_bfloat16* agg = (__hip_bfloat16*)((char*)d_ws + agg_off);
        unsigned* packed = (unsigned*)agg;
        bucket_scatter<<<BB, 256, 0, stream>>>(src, dst, bcursor, packed, n_edges);
        bucket_csr<<<NBUCK, 256, 0, stream>>>(packed, bstart, row_start, esrc);

        gather_kernel<__hip_bfloat16><<<GB, 256, 0, stream>>>(x, row_start, esrc, agg);
        dense_kernel<__hip_bfloat16, 1><<<DB, 256, 0, stream>>>(agg, x, Wrel1, brel1, Wroot1, out);
        gather_kernel<__hip_bfloat16><<<GB, 256, 0, stream>>>(out, row_start, esrc, agg);
        dense_kernel<__hip_bfloat16, 0><<<DB, 256, 0, stream>>>(agg, out, Wrel2, brel2, Wroot2, out);
    }
}

// Round 14
// 277.091 us; speedup vs baseline: 5.6021x; 1.1891x over previous
//
#include <hip/hip_runtime.h>
#include <hip/hip_bf16.h>

#define N_NODES 100000
#define SCAN_N (N_NODES + 1)
#define D 64
#define NBUCK 256
#define BSH 9
#define BNODES (1 << BSH)
#define EPB 2048

// ---------------- bucketed CSR build (unchanged from round 13) --------------

__global__ __launch_bounds__(256) void bucket_count(
    const int* __restrict__ dst, int* __restrict__ bcount, int n_edges)
{
    __shared__ int lh[NBUCK];
    const int t = threadIdx.x;
    lh[t] = 0;
    __syncthreads();
    const int e0 = blockIdx.x * EPB;
    const int e1 = min(e0 + EPB, n_edges);
    for (int e = e0 + t; e < e1; e += 256)
        atomicAdd(&lh[dst[e] >> BSH], 1);
    __syncthreads();
    if (lh[t]) atomicAdd(&bcount[t], lh[t]);
}

__global__ __launch_bounds__(256) void bucket_scan(
    const int* __restrict__ bcount, int* __restrict__ bstart,
    int* __restrict__ bcursor)
{
    __shared__ int tmp[256];
    const int t = threadIdx.x;
    const int v = bcount[t];
    tmp[t] = v;
    __syncthreads();
    for (int off = 1; off < 256; off <<= 1) {
        const int u = (t >= off) ? tmp[t - off] : 0;
        __syncthreads();
        tmp[t] += u;
        __syncthreads();
    }
    const int excl = tmp[t] - v;
    bstart[t] = excl;
    bcursor[t] = excl;
    if (t == 255) bstart[256] = tmp[255];
}

__global__ __launch_bounds__(256) void bucket_scatter(
    const int* __restrict__ src, const int* __restrict__ dst,
    int* __restrict__ bcursor, unsigned* __restrict__ packed, int n_edges)
{
    __shared__ int lh[NBUCK];
    __shared__ int lb[NBUCK];
    const int t = threadIdx.x;
    lh[t] = 0;
    __syncthreads();
    const int e0 = blockIdx.x * EPB;
    const int e1 = min(e0 + EPB, n_edges);
    for (int e = e0 + t; e < e1; e += 256)
        atomicAdd(&lh[dst[e] >> BSH], 1);
    __syncthreads();
    const int cnt = lh[t];
    lb[t] = cnt ? atomicAdd(&bcursor[t], cnt) : 0;
    __syncthreads();
    lh[t] = lb[t];
    __syncthreads();
    for (int e = e0 + t; e < e1; e += 256) {
        const int d = dst[e];
        const int pos = atomicAdd(&lh[d >> BSH], 1);
        packed[pos] = ((unsigned)src[e] << BSH) | (unsigned)(d & (BNODES - 1));
    }
}

__global__ __launch_bounds__(256) void bucket_csr(
    const unsigned* __restrict__ packed,
    const int* __restrict__ bstart,
    int* __restrict__ row_start,
    int* __restrict__ esrc)
{
    __shared__ int lcnt[BNODES];
    __shared__ int pair[256];
    const int b = blockIdx.x;
    const int t = threadIdx.x;
    const int beg = bstart[b];
    const int end = bstart[b + 1];

    lcnt[t] = 0; lcnt[t + 256] = 0;
    __syncthreads();
    for (int e = beg + t; e < end; e += 256)
        atomicAdd(&lcnt[packed[e] & (BNODES - 1)], 1);
    __syncthreads();

    const int v0 = lcnt[2 * t], v1 = lcnt[2 * t + 1];
    pair[t] = v0 + v1;
    __syncthreads();
    for (int off = 1; off < 256; off <<= 1) {
        const int u = (t >= off) ? pair[t - off] : 0;
        __syncthreads();
        pair[t] += u;
        __syncthreads();
    }
    const int pexcl = pair[t] - (v0 + v1);
    __syncthreads();
    lcnt[2 * t]     = pexcl;
    lcnt[2 * t + 1] = pexcl + v0;
    __syncthreads();

    {
        const int l0 = 2 * t, l1 = 2 * t + 1;
        const int n0 = b * BNODES + l0, n1 = b * BNODES + l1;
        if (n0 <= N_NODES) row_start[n0] = beg + lcnt[l0];
        if (n1 <= N_NODES) row_start[n1] = beg + lcnt[l1];
        lcnt[l0] += beg;
        lcnt[l1] += beg;
    }
    __syncthreads();
    for (int e = beg + t; e < end; e += 256) {
        const unsigned p = packed[e];
        const int pos = atomicAdd(&lcnt[p & (BNODES - 1)], 1);
        esrc[pos] = (int)(p >> BSH);
    }
}

// ---------------- W pre-transpose: WT[m][k*64+j] = W_m[j*64+k] --------------

__global__ __launch_bounds__(256) void wt_kernel(
    const float* __restrict__ W0, const float* __restrict__ W1,
    const float* __restrict__ W2, const float* __restrict__ W3,
    float* __restrict__ WT)
{
    const float* W = (blockIdx.x == 0) ? W0 : (blockIdx.x == 1) ? W1
                   : (blockIdx.x == 2) ? W2 : W3;
    float* O = WT + blockIdx.x * 4096;
    __shared__ float tile[64][65];
    const int t = threadIdx.x;
    for (int i = t; i < 4096; i += 256) tile[i >> 6][i & 63] = W[i];   // coalesced
    __syncthreads();
    for (int i = t; i < 4096; i += 256) O[i] = tile[i & 63][i >> 6];   // coalesced, LDS stride-65
}

// ---------------- type helpers ----------------------------------------------

__device__ __forceinline__ float4 ld4(const float* p) {
    return *reinterpret_cast<const float4*>(p);
}
__device__ __forceinline__ float4 ld4(const __hip_bfloat16* p) {
    const ushort4 u = *reinterpret_cast<const ushort4*>(p);
    float4 v;
    v.x = __uint_as_float((unsigned)u.x << 16);
    v.y = __uint_as_float((unsigned)u.y << 16);
    v.z = __uint_as_float((unsigned)u.z << 16);
    v.w = __uint_as_float((unsigned)u.w << 16);
    return v;
}
__device__ __forceinline__ void st4(float* p, float4 v) { *reinterpret_cast<float4*>(p) = v; }
__device__ __forceinline__ void st4(__hip_bfloat16* p, float4 v) {
    p[0] = __float2bfloat16(v.x); p[1] = __float2bfloat16(v.y);
    p[2] = __float2bfloat16(v.z); p[3] = __float2bfloat16(v.w);
}
__device__ __forceinline__ void fma4(float4& acc, float s, const float4& w) {
    acc.x += s * w.x; acc.y += s * w.y; acc.z += s * w.z; acc.w += s * w.w;
}

// ---------------- gather: agg[i] = sum_{j->i} xin[j] ------------------------

template <typename IT, typename AT>
__global__ __launch_bounds__(256) void gather_kernel(
    const IT* __restrict__ xin,
    const int* __restrict__ row_start,
    const int* __restrict__ esrc,
    AT* __restrict__ agg)
{
    const int wid = (blockIdx.x * 256 + threadIdx.x) >> 6;   // node
    if (wid >= N_NODES) return;
    const int lane = threadIdx.x & 63;
    const int g = lane >> 4;
    const int c = lane & 15;

    const int beg = row_start[wid];
    const int end = row_start[wid + 1];

    float4 acc = make_float4(0.f, 0.f, 0.f, 0.f);
    for (int e = beg; e < end; e += 8) {
        const int i0 = e + g;
        const int i1 = e + 4 + g;
        if (i0 < end) {
            const float4 v = ld4(&xin[(long)esrc[i0] * D + c * 4]);
            acc.x += v.x; acc.y += v.y; acc.z += v.z; acc.w += v.w;
        }
        if (i1 < end) {
            const float4 v = ld4(&xin[(long)esrc[i1] * D + c * 4]);
            acc.x += v.x; acc.y += v.y; acc.z += v.z; acc.w += v.w;
        }
    }
    acc.x += __shfl_xor(acc.x, 16); acc.y += __shfl_xor(acc.y, 16);
    acc.z += __shfl_xor(acc.z, 16); acc.w += __shfl_xor(acc.w, 16);
    acc.x += __shfl_xor(acc.x, 32); acc.y += __shfl_xor(acc.y, 32);
    acc.z += __shfl_xor(acc.z, 32); acc.w += __shfl_xor(acc.w, 32);

    if (g == 0) st4(&agg[(long)wid * D + c * 4], acc);
}

// ---------------- dense: out = [relu]([agg|x] @ [Wrel|Wroot]^T + b) ---------
// WT pre-transposed -> coalesced staging, identity LDS layout. Single-half
// Wlds (16 KB) + Alds (17 KB) = 34 KB -> 4 blocks/CU. 128-VGPR cap.
#define AS 68
template <typename AT, typename IT, typename OT, int RELU>
__global__ __launch_bounds__(256, 4) void dense_kernel(
    const AT* __restrict__ agg,
    const IT* __restrict__ xin,
    const float* __restrict__ WT,    // [2][4096]: relT then rootT, k-major
    const float* __restrict__ brel,
    OT* __restrict__ out)
{
    __shared__ float Wlds[64 * 64];
    __shared__ float Alds[64 * AS];

    const int t = threadIdx.x;
    const int tc = t & 15;
    const int tn = t >> 4;
    const int node0 = blockIdx.x * 64;

    const float4 bias = *reinterpret_cast<const float4*>(&brel[tc * 4]);
    float4 acc0 = bias, acc1 = bias, acc2 = bias, acc3 = bias;

#pragma unroll
    for (int half = 0; half < 2; ++half) {
        __syncthreads();   // protect Wlds/Alds reuse
        for (int i = t; i < 1024; i += 256)   // W half: coalesced float4
            *reinterpret_cast<float4*>(&Wlds[i * 4]) =
                *reinterpret_cast<const float4*>(&WT[half * 4096 + i * 4]);
        for (int i = t; i < 1024; i += 256) { // A half: 64 nodes x 16 float4
            const int n = i >> 4, kq = i & 15;
            int gn = node0 + n; if (gn > N_NODES - 1) gn = N_NODES - 1;
            float4 v;
            if (half == 0) v = ld4(&agg[(long)gn * D + kq * 4]);
            else           v = ld4(&xin[(long)gn * D + kq * 4]);
            *reinterpret_cast<float4*>(&Alds[n * AS + kq * 4]) = v;
        }
        __syncthreads();

#pragma unroll 4
        for (int kb = 0; kb < 64; kb += 4) {
            const float4 w0 = *reinterpret_cast<const float4*>(&Wlds[(kb + 0) * 64 + tc * 4]);
            const float4 w1 = *reinterpret_cast<const float4*>(&Wlds[(kb + 1) * 64 + tc * 4]);
            const float4 w2 = *reinterpret_cast<const float4*>(&Wlds[(kb + 2) * 64 + tc * 4]);
            const float4 w3 = *reinterpret_cast<const float4*>(&Wlds[(kb + 3) * 64 + tc * 4]);
            const float4 a0 = *reinterpret_cast<const float4*>(&Alds[(tn * 4 + 0) * AS + kb]);
            const float4 a1 = *reinterpret_cast<const float4*>(&Alds[(tn * 4 + 1) * AS + kb]);
            const float4 a2 = *reinterpret_cast<const float4*>(&Alds[(tn * 4 + 2) * AS + kb]);
            const float4 a3 = *reinterpret_cast<const float4*>(&Alds[(tn * 4 + 3) * AS + kb]);
            fma4(acc0, a0.x, w0); fma4(acc0, a0.y, w1); fma4(acc0, a0.z, w2); fma4(acc0, a0.w, w3);
            fma4(acc1, a1.x, w0); fma4(acc1, a1.y, w1); fma4(acc1, a1.z, w2); fma4(acc1, a1.w, w3);
            fma4(acc2, a2.x, w0); fma4(acc2, a2.y, w1); fma4(acc2, a2.z, w2); fma4(acc2, a2.w, w3);
            fma4(acc3, a3.x, w0); fma4(acc3, a3.y, w1); fma4(acc3, a3.z, w2); fma4(acc3, a3.w, w3);
        }
    }

    float4 r[4] = {acc0, acc1, acc2, acc3};
#pragma unroll
    for (int i = 0; i < 4; ++i) {
        if (RELU) {
            r[i].x = fmaxf(r[i].x, 0.f); r[i].y = fmaxf(r[i].y, 0.f);
            r[i].z = fmaxf(r[i].z, 0.f); r[i].w = fmaxf(r[i].w, 0.f);
        }
        const int gn = node0 + tn * 4 + i;
        if (gn < N_NODES)
            st4(&out[(long)gn * D + tc * 4], r[i]);
    }
}

// ---------------------------------------------------------------------------

extern "C" void kernel_launch(void* const* d_in, const int* in_sizes, int n_in,
                              void* d_out, int out_size, void* d_ws, size_t ws_size,
                              hipStream_t stream)
{
    const float* x     = (const float*)d_in[0];
    const int*   ei    = (const int*)d_in[1];
    const float* Wrel1 = (const float*)d_in[2];
    const float* brel1 = (const float*)d_in[3];
    const float* Wroot1= (const float*)d_in[4];
    const float* Wrel2 = (const float*)d_in[5];
    const float* brel2 = (const float*)d_in[6];
    const float* Wroot2= (const float*)d_in[7];
    float* out = (float*)d_out;

    const int n_edges = in_sizes[1] / 2;
    const int* src = ei;
    const int* dst = ei + n_edges;

    // workspace layout (int units)
    int* base      = (int*)d_ws;
    int* row_start = base;                        // 100352 (padded)
    int* bstart    = base + 100352;               // 320
    int* bcursor   = base + 100672;               // 256
    int* bcount    = base + 100928;               // 256
    float* WT      = (float*)(base + 101184);     // 4*4096 = 16384
    int* esrc      = base + 117568;               // n_edges
    const size_t agg_off = (((size_t)(117568 + n_edges) * 4) + 255) & ~(size_t)255;
    const size_t aggf32_bytes = (size_t)N_NODES * D * 4;
    const size_t aggbf_bytes  = (size_t)N_NODES * D * 2;
    const size_t h_bytes      = (size_t)N_NODES * D * 2;   // h always bf16

    const size_t need_f32 = agg_off + aggf32_bytes + h_bytes + 1024;
    const size_t need_bf  = agg_off + aggbf_bytes  + h_bytes + 1024;

    const int BB = (n_edges + EPB - 1) / EPB;
    hipMemsetAsync(bcount, 0, NBUCK * sizeof(int), stream);
    bucket_count<<<BB, 256, 0, stream>>>(dst, bcount, n_edges);
    bucket_scan<<<1, 256, 0, stream>>>(bcount, bstart, bcursor);
    wt_kernel<<<4, 256, 0, stream>>>(Wrel1, Wroot1, Wrel2, Wroot2, WT);

    const int GB = (N_NODES * 64 + 255) / 256;
    const int DB = (N_NODES + 63) / 64;

    if (ws_size >= need_f32) {
        float* agg = (float*)((char*)d_ws + agg_off);
        __hip_bfloat16* h = (__hip_bfloat16*)((char*)d_ws + agg_off + aggf32_bytes);
        unsigned* packed = (unsigned*)agg;   // consumed before gather overwrites
        bucket_scatter<<<BB, 256, 0, stream>>>(src, dst, bcursor, packed, n_edges);
        bucket_csr<<<NBUCK, 256, 0, stream>>>(packed, bstart, row_start, esrc);

        gather_kernel<float, float><<<GB, 256, 0, stream>>>(x, row_start, esrc, agg);
        dense_kernel<float, float, __hip_bfloat16, 1><<<DB, 256, 0, stream>>>(
            agg, x, WT, brel1, h);
        gather_kernel<__hip_bfloat16, float><<<GB, 256, 0, stream>>>(h, row_start, esrc, agg);
        dense_kernel<float, __hip_bfloat16, float, 0><<<DB, 256, 0, stream>>>(
            agg, h, WT + 8192, brel2, out);
    } else {
        __hip_bfloat16* agg = (__hip_bfloat16*)((char*)d_ws + agg_off);
        __hip_bfloat16* h = (__hip_bfloat16*)((char*)d_ws + agg_off + aggbf_bytes);
        unsigned* packed = (unsigned*)agg;
        bucket_scatter<<<BB, 256, 0, stream>>>(src, dst, bcursor, packed, n_edges);
        bucket_csr<<<NBUCK, 256, 0, stream>>>(packed, bstart, row_start, esrc);

        gather_kernel<float, __hip_bfloat16><<<GB, 256, 0, stream>>>(x, row_start, esrc, agg);
        dense_kernel<__hip_bfloat16, float, __hip_bfloat16, 1><<<DB, 256, 0, stream>>>(
            agg, x, WT, brel1, h);
        gather_kernel<__hip_bfloat16, __hip_bfloat16><<<GB, 256, 0, stream>>>(h, row_start, esrc, agg);
        dense_kernel<__hip_bfloat16, __hip_bfloat16, float, 0><<<DB, 256, 0, stream>>>(
            agg, h, WT + 8192, brel2, out);
    }
}

// Round 15
// 247.963 us; speedup vs baseline: 6.2602x; 1.1175x over previous
//
#include <hip/hip_runtime.h>
#include <hip/hip_bf16.h>

#define N_NODES 100000
#define SCAN_N (N_NODES + 1)
#define D 64
#define NBUCK 256
#define BSH 9
#define BNODES (1 << BSH)
#define EPB 2048

// ---------------- bucketed CSR build (unchanged) ----------------------------

__global__ __launch_bounds__(256) void bucket_count(
    const int* __restrict__ dst, int* __restrict__ bcount, int n_edges)
{
    __shared__ int lh[NBUCK];
    const int t = threadIdx.x;
    lh[t] = 0;
    __syncthreads();
    const int e0 = blockIdx.x * EPB;
    const int e1 = min(e0 + EPB, n_edges);
    for (int e = e0 + t; e < e1; e += 256)
        atomicAdd(&lh[dst[e] >> BSH], 1);
    __syncthreads();
    if (lh[t]) atomicAdd(&bcount[t], lh[t]);
}

__global__ __launch_bounds__(256) void bucket_scan(
    const int* __restrict__ bcount, int* __restrict__ bstart,
    int* __restrict__ bcursor)
{
    __shared__ int tmp[256];
    const int t = threadIdx.x;
    const int v = bcount[t];
    tmp[t] = v;
    __syncthreads();
    for (int off = 1; off < 256; off <<= 1) {
        const int u = (t >= off) ? tmp[t - off] : 0;
        __syncthreads();
        tmp[t] += u;
        __syncthreads();
    }
    const int excl = tmp[t] - v;
    bstart[t] = excl;
    bcursor[t] = excl;
    if (t == 255) bstart[256] = tmp[255];
}

__global__ __launch_bounds__(256) void bucket_scatter(
    const int* __restrict__ src, const int* __restrict__ dst,
    int* __restrict__ bcursor, unsigned* __restrict__ packed, int n_edges)
{
    __shared__ int lh[NBUCK];
    __shared__ int lb[NBUCK];
    const int t = threadIdx.x;
    lh[t] = 0;
    __syncthreads();
    const int e0 = blockIdx.x * EPB;
    const int e1 = min(e0 + EPB, n_edges);
    for (int e = e0 + t; e < e1; e += 256)
        atomicAdd(&lh[dst[e] >> BSH], 1);
    __syncthreads();
    const int cnt = lh[t];
    lb[t] = cnt ? atomicAdd(&bcursor[t], cnt) : 0;
    __syncthreads();
    lh[t] = lb[t];
    __syncthreads();
    for (int e = e0 + t; e < e1; e += 256) {
        const int d = dst[e];
        const int pos = atomicAdd(&lh[d >> BSH], 1);
        packed[pos] = ((unsigned)src[e] << BSH) | (unsigned)(d & (BNODES - 1));
    }
}

__global__ __launch_bounds__(256) void bucket_csr(
    const unsigned* __restrict__ packed,
    const int* __restrict__ bstart,
    int* __restrict__ row_start,
    int* __restrict__ esrc)
{
    __shared__ int lcnt[BNODES];
    __shared__ int pair[256];
    const int b = blockIdx.x;
    const int t = threadIdx.x;
    const int beg = bstart[b];
    const int end = bstart[b + 1];

    lcnt[t] = 0; lcnt[t + 256] = 0;
    __syncthreads();
    for (int e = beg + t; e < end; e += 256)
        atomicAdd(&lcnt[packed[e] & (BNODES - 1)], 1);
    __syncthreads();

    const int v0 = lcnt[2 * t], v1 = lcnt[2 * t + 1];
    pair[t] = v0 + v1;
    __syncthreads();
    for (int off = 1; off < 256; off <<= 1) {
        const int u = (t >= off) ? pair[t - off] : 0;
        __syncthreads();
        pair[t] += u;
        __syncthreads();
    }
    const int pexcl = pair[t] - (v0 + v1);
    __syncthreads();
    lcnt[2 * t]     = pexcl;
    lcnt[2 * t + 1] = pexcl + v0;
    __syncthreads();

    {
        const int l0 = 2 * t, l1 = 2 * t + 1;
        const int n0 = b * BNODES + l0, n1 = b * BNODES + l1;
        if (n0 <= N_NODES) row_start[n0] = beg + lcnt[l0];
        if (n1 <= N_NODES) row_start[n1] = beg + lcnt[l1];
        lcnt[l0] += beg;
        lcnt[l1] += beg;
    }
    __syncthreads();
    for (int e = beg + t; e < end; e += 256) {
        const unsigned p = packed[e];
        const int pos = atomicAdd(&lcnt[p & (BNODES - 1)], 1);
        esrc[pos] = (int)(p >> BSH);
    }
}

// ---------------- W pre-transpose -------------------------------------------

__global__ __launch_bounds__(256) void wt_kernel(
    const float* __restrict__ W0, const float* __restrict__ W1,
    const float* __restrict__ W2, const float* __restrict__ W3,
    float* __restrict__ WT)
{
    const float* W = (blockIdx.x == 0) ? W0 : (blockIdx.x == 1) ? W1
                   : (blockIdx.x == 2) ? W2 : W3;
    float* O = WT + blockIdx.x * 4096;
    __shared__ float tile[64][65];
    const int t = threadIdx.x;
    for (int i = t; i < 4096; i += 256) tile[i >> 6][i & 63] = W[i];
    __syncthreads();
    for (int i = t; i < 4096; i += 256) O[i] = tile[i & 63][i >> 6];
}

// ---------------- helpers ----------------------------------------------------

__device__ __forceinline__ float uasf(unsigned u) { return __uint_as_float(u); }
__device__ __forceinline__ unsigned f2bf(float f) {
    __hip_bfloat16 b = __float2bfloat16(f);
    return (unsigned)*reinterpret_cast<unsigned short*>(&b);
}
__device__ __forceinline__ float4 ld4(const float* p) {
    return *reinterpret_cast<const float4*>(p);
}
__device__ __forceinline__ float4 ld4(const __hip_bfloat16* p) {
    const ushort4 u = *reinterpret_cast<const ushort4*>(p);
    float4 v;
    v.x = uasf((unsigned)u.x << 16);
    v.y = uasf((unsigned)u.y << 16);
    v.z = uasf((unsigned)u.z << 16);
    v.w = uasf((unsigned)u.w << 16);
    return v;
}
__device__ __forceinline__ void st4(float* p, float4 v) { *reinterpret_cast<float4*>(p) = v; }
__device__ __forceinline__ void st4(__hip_bfloat16* p, float4 v) {
    p[0] = __float2bfloat16(v.x); p[1] = __float2bfloat16(v.y);
    p[2] = __float2bfloat16(v.z); p[3] = __float2bfloat16(v.w);
}
__device__ __forceinline__ void fma4(float4& acc, float s, const float4& w) {
    acc.x += s * w.x; acc.y += s * w.y; acc.z += s * w.z; acc.w += s * w.w;
}

// ---------------- x -> bf16 copy --------------------------------------------

__global__ __launch_bounds__(256) void tobf_kernel(
    const float* __restrict__ in, unsigned short* __restrict__ out, int n8)
{
    const int i = blockIdx.x * 256 + threadIdx.x;
    if (i >= n8) return;
    const float4 v0 = *reinterpret_cast<const float4*>(&in[(long)i * 8]);
    const float4 v1 = *reinterpret_cast<const float4*>(&in[(long)i * 8 + 4]);
    uint4 o;
    o.x = f2bf(v0.x) | (f2bf(v0.y) << 16);
    o.y = f2bf(v0.z) | (f2bf(v0.w) << 16);
    o.z = f2bf(v1.x) | (f2bf(v1.y) << 16);
    o.w = f2bf(v1.z) | (f2bf(v1.w) << 16);
    *reinterpret_cast<uint4*>(&out[(long)i * 8]) = o;
}

// ---------------- gather (bf16 rows, 128B): agg[i] = sum_{j->i} xin[j] ------
// One wave per node. lane = g*8+c: 8 edge slots x 8 ushort8 chunks.
// Each lane-load is 16B covering 1/2 cache line; 8 loads cover a row
// (vs 16 in round 14) -> half the request/issue cost per edge.
__global__ __launch_bounds__(256) void gather_bf(
    const unsigned short* __restrict__ xin,   // bf16 rows, 64 elems
    const int* __restrict__ row_start,
    const int* __restrict__ esrc,
    unsigned short* __restrict__ agg)         // bf16 rows
{
    const int wid = (blockIdx.x * 256 + threadIdx.x) >> 6;
    if (wid >= N_NODES) return;
    const int lane = threadIdx.x & 63;
    const int g = lane >> 3;      // 0..7 edge slot
    const int c = lane & 7;       // 0..7 16B chunk

    const int beg = row_start[wid];
    const int end = row_start[wid + 1];

    float a0 = 0.f, a1 = 0.f, a2 = 0.f, a3 = 0.f,
          a4 = 0.f, a5 = 0.f, a6 = 0.f, a7 = 0.f;
    for (int e = beg; e < end; e += 16) {
        const int i0 = e + g;
        const int i1 = e + 8 + g;
        if (i0 < end) {
            const uint4 u = *reinterpret_cast<const uint4*>(
                &xin[(long)esrc[i0] * D + c * 8]);
            a0 += uasf(u.x << 16); a1 += uasf(u.x & 0xFFFF0000u);
            a2 += uasf(u.y << 16); a3 += uasf(u.y & 0xFFFF0000u);
            a4 += uasf(u.z << 16); a5 += uasf(u.z & 0xFFFF0000u);
            a6 += uasf(u.w << 16); a7 += uasf(u.w & 0xFFFF0000u);
        }
        if (i1 < end) {
            const uint4 u = *reinterpret_cast<const uint4*>(
                &xin[(long)esrc[i1] * D + c * 8]);
            a0 += uasf(u.x << 16); a1 += uasf(u.x & 0xFFFF0000u);
            a2 += uasf(u.y << 16); a3 += uasf(u.y & 0xFFFF0000u);
            a4 += uasf(u.z << 16); a5 += uasf(u.z & 0xFFFF0000u);
            a6 += uasf(u.w << 16); a7 += uasf(u.w & 0xFFFF0000u);
        }
    }
#pragma unroll
    for (int m = 8; m <= 32; m <<= 1) {
        a0 += __shfl_xor(a0, m); a1 += __shfl_xor(a1, m);
        a2 += __shfl_xor(a2, m); a3 += __shfl_xor(a3, m);
        a4 += __shfl_xor(a4, m); a5 += __shfl_xor(a5, m);
        a6 += __shfl_xor(a6, m); a7 += __shfl_xor(a7, m);
    }
    if (g == 0) {
        uint4 o;
        o.x = f2bf(a0) | (f2bf(a1) << 16);
        o.y = f2bf(a2) | (f2bf(a3) << 16);
        o.z = f2bf(a4) | (f2bf(a5) << 16);
        o.w = f2bf(a6) | (f2bf(a7) << 16);
        *reinterpret_cast<uint4*>(&agg[(long)wid * D + c * 8]) = o;
    }
}

// ---------------- dense: out = [relu]([agg|x] @ [Wrel|Wroot]^T + b) ---------

#define AS 68
template <typename AT, typename IT, typename OT, int RELU>
__global__ __launch_bounds__(256, 4) void dense_kernel(
    const AT* __restrict__ agg,
    const IT* __restrict__ xin,
    const float* __restrict__ WT,    // [2][4096]: relT then rootT, k-major
    const float* __restrict__ brel,
    OT* __restrict__ out)
{
    __shared__ float Wlds[64 * 64];
    __shared__ float Alds[64 * AS];

    const int t = threadIdx.x;
    const int tc = t & 15;
    const int tn = t >> 4;
    const int node0 = blockIdx.x * 64;

    const float4 bias = *reinterpret_cast<const float4*>(&brel[tc * 4]);
    float4 acc0 = bias, acc1 = bias, acc2 = bias, acc3 = bias;

#pragma unroll
    for (int half = 0; half < 2; ++half) {
        __syncthreads();
        for (int i = t; i < 1024; i += 256)
            *reinterpret_cast<float4*>(&Wlds[i * 4]) =
                *reinterpret_cast<const float4*>(&WT[half * 4096 + i * 4]);
        for (int i = t; i < 1024; i += 256) {
            const int n = i >> 4, kq = i & 15;
            int gn = node0 + n; if (gn > N_NODES - 1) gn = N_NODES - 1;
            float4 v;
            if (half == 0) v = ld4(&agg[(long)gn * D + kq * 4]);
            else           v = ld4(&xin[(long)gn * D + kq * 4]);
            *reinterpret_cast<float4*>(&Alds[n * AS + kq * 4]) = v;
        }
        __syncthreads();

#pragma unroll 4
        for (int kb = 0; kb < 64; kb += 4) {
            const float4 w0 = *reinterpret_cast<const float4*>(&Wlds[(kb + 0) * 64 + tc * 4]);
            const float4 w1 = *reinterpret_cast<const float4*>(&Wlds[(kb + 1) * 64 + tc * 4]);
            const float4 w2 = *reinterpret_cast<const float4*>(&Wlds[(kb + 2) * 64 + tc * 4]);
            const float4 w3 = *reinterpret_cast<const float4*>(&Wlds[(kb + 3) * 64 + tc * 4]);
            const float4 a0 = *reinterpret_cast<const float4*>(&Alds[(tn * 4 + 0) * AS + kb]);
            const float4 a1 = *reinterpret_cast<const float4*>(&Alds[(tn * 4 + 1) * AS + kb]);
            const float4 a2 = *reinterpret_cast<const float4*>(&Alds[(tn * 4 + 2) * AS + kb]);
            const float4 a3 = *reinterpret_cast<const float4*>(&Alds[(tn * 4 + 3) * AS + kb]);
            fma4(acc0, a0.x, w0); fma4(acc0, a0.y, w1); fma4(acc0, a0.z, w2); fma4(acc0, a0.w, w3);
            fma4(acc1, a1.x, w0); fma4(acc1, a1.y, w1); fma4(acc1, a1.z, w2); fma4(acc1, a1.w, w3);
            fma4(acc2, a2.x, w0); fma4(acc2, a2.y, w1); fma4(acc2, a2.z, w2); fma4(acc2, a2.w, w3);
            fma4(acc3, a3.x, w0); fma4(acc3, a3.y, w1); fma4(acc3, a3.z, w2); fma4(acc3, a3.w, w3);
        }
    }

    float4 r[4] = {acc0, acc1, acc2, acc3};
#pragma unroll
    for (int i = 0; i < 4; ++i) {
        if (RELU) {
            r[i].x = fmaxf(r[i].x, 0.f); r[i].y = fmaxf(r[i].y, 0.f);
            r[i].z = fmaxf(r[i].z, 0.f); r[i].w = fmaxf(r[i].w, 0.f);
        }
        const int gn = node0 + tn * 4 + i;
        if (gn < N_NODES)
            st4(&out[(long)gn * D + tc * 4], r[i]);
    }
}

// ---------------------------------------------------------------------------

extern "C" void kernel_launch(void* const* d_in, const int* in_sizes, int n_in,
                              void* d_out, int out_size, void* d_ws, size_t ws_size,
                              hipStream_t stream)
{
    const float* x     = (const float*)d_in[0];
    const int*   ei    = (const int*)d_in[1];
    const float* Wrel1 = (const float*)d_in[2];
    const float* brel1 = (const float*)d_in[3];
    const float* Wroot1= (const float*)d_in[4];
    const float* Wrel2 = (const float*)d_in[5];
    const float* brel2 = (const float*)d_in[6];
    const float* Wroot2= (const float*)d_in[7];
    float* out = (float*)d_out;

    const int n_edges = in_sizes[1] / 2;
    const int* src = ei;
    const int* dst = ei + n_edges;

    // workspace layout (int units)
    int* base      = (int*)d_ws;
    int* row_start = base;                        // 100352 (padded)
    int* bstart    = base + 100352;               // 320
    int* bcursor   = base + 100672;               // 256
    int* bcount    = base + 100928;               // 256
    float* WT      = (float*)(base + 101184);     // 16384
    int* esrc      = base + 117568;               // n_edges
    const size_t xbf_off = (((size_t)(117568 + n_edges) * 4) + 255) & ~(size_t)255;
    const size_t row_bf  = (size_t)N_NODES * D * 2;     // 12.8 MB
    const size_t agg_off = xbf_off + row_bf;
    const size_t h_off   = agg_off + row_bf;
    // total need = xbf_off + 3*row_bf ~= 45.3 MB (== round-14 footprint, fits)

    unsigned short* xbf = (unsigned short*)((char*)d_ws + xbf_off);
    unsigned short* agg = (unsigned short*)((char*)d_ws + agg_off);
    unsigned short* h   = (unsigned short*)((char*)d_ws + h_off);
    unsigned* packed    = (unsigned*)agg;   // consumed by bucket_csr before gather1

    const int BB = (n_edges + EPB - 1) / EPB;
    hipMemsetAsync(bcount, 0, NBUCK * sizeof(int), stream);
    bucket_count<<<BB, 256, 0, stream>>>(dst, bcount, n_edges);
    bucket_scan<<<1, 256, 0, stream>>>(bcount, bstart, bcursor);
    wt_kernel<<<4, 256, 0, stream>>>(Wrel1, Wroot1, Wrel2, Wroot2, WT);
    tobf_kernel<<<(N_NODES * D / 8 + 255) / 256, 256, 0, stream>>>(x, xbf, N_NODES * D / 8);
    bucket_scatter<<<BB, 256, 0, stream>>>(src, dst, bcursor, packed, n_edges);
    bucket_csr<<<NBUCK, 256, 0, stream>>>(packed, bstart, row_start, esrc);

    const int GB = (N_NODES * 64 + 255) / 256;   // wave per node
    const int DB = (N_NODES + 63) / 64;

    // layer 1
    gather_bf<<<GB, 256, 0, stream>>>(xbf, row_start, esrc, agg);
    dense_kernel<__hip_bfloat16, float, __hip_bfloat16, 1><<<DB, 256, 0, stream>>>(
        (const __hip_bfloat16*)agg, x, WT, brel1, (__hip_bfloat16*)h);
    // layer 2
    gather_bf<<<GB, 256, 0, stream>>>(h, row_start, esrc, agg);
    dense_kernel<__hip_bfloat16, __hip_bfloat16, float, 0><<<DB, 256, 0, stream>>>(
        (const __hip_bfloat16*)agg, (const __hip_bfloat16*)h, WT + 8192, brel2, out);
}

// Round 17
// 207.824 us; speedup vs baseline: 7.4693x; 1.1931x over previous
//
#include <hip/hip_runtime.h>
#include <hip/hip_bf16.h>

#define N_NODES 100000
#define SCAN_N (N_NODES + 1)
#define D 64
#define NBUCK 256
#define BSH 9
#define BNODES (1 << BSH)
#define EPB 2048

typedef __attribute__((ext_vector_type(8))) short bf16x8;
typedef __attribute__((ext_vector_type(4))) float f32x4;

// ---------------- bucketed CSR build (unchanged) ----------------------------

__global__ __launch_bounds__(256) void bucket_count(
    const int* __restrict__ dst, int* __restrict__ bcount, int n_edges)
{
    __shared__ int lh[NBUCK];
    const int t = threadIdx.x;
    lh[t] = 0;
    __syncthreads();
    const int e0 = blockIdx.x * EPB;
    const int e1 = min(e0 + EPB, n_edges);
    for (int e = e0 + t; e < e1; e += 256)
        atomicAdd(&lh[dst[e] >> BSH], 1);
    __syncthreads();
    if (lh[t]) atomicAdd(&bcount[t], lh[t]);
}

__global__ __launch_bounds__(256) void bucket_scan(
    const int* __restrict__ bcount, int* __restrict__ bstart,
    int* __restrict__ bcursor)
{
    __shared__ int tmp[256];
    const int t = threadIdx.x;
    const int v = bcount[t];
    tmp[t] = v;
    __syncthreads();
    for (int off = 1; off < 256; off <<= 1) {
        const int u = (t >= off) ? tmp[t - off] : 0;
        __syncthreads();
        tmp[t] += u;
        __syncthreads();
    }
    const int excl = tmp[t] - v;
    bstart[t] = excl;
    bcursor[t] = excl;
    if (t == 255) bstart[256] = tmp[255];
}

__global__ __launch_bounds__(256) void bucket_scatter(
    const int* __restrict__ src, const int* __restrict__ dst,
    int* __restrict__ bcursor, unsigned* __restrict__ packed, int n_edges)
{
    __shared__ int lh[NBUCK];
    __shared__ int lb[NBUCK];
    const int t = threadIdx.x;
    lh[t] = 0;
    __syncthreads();
    const int e0 = blockIdx.x * EPB;
    const int e1 = min(e0 + EPB, n_edges);
    for (int e = e0 + t; e < e1; e += 256)
        atomicAdd(&lh[dst[e] >> BSH], 1);
    __syncthreads();
    const int cnt = lh[t];
    lb[t] = cnt ? atomicAdd(&bcursor[t], cnt) : 0;
    __syncthreads();
    lh[t] = lb[t];
    __syncthreads();
    for (int e = e0 + t; e < e1; e += 256) {
        const int d = dst[e];
        const int pos = atomicAdd(&lh[d >> BSH], 1);
        packed[pos] = ((unsigned)src[e] << BSH) | (unsigned)(d & (BNODES - 1));
    }
}

__global__ __launch_bounds__(256) void bucket_csr(
    const unsigned* __restrict__ packed,
    const int* __restrict__ bstart,
    int* __restrict__ row_start,
    int* __restrict__ esrc)
{
    __shared__ int lcnt[BNODES];
    __shared__ int pair[256];
    const int b = blockIdx.x;
    const int t = threadIdx.x;
    const int beg = bstart[b];
    const int end = bstart[b + 1];

    lcnt[t] = 0; lcnt[t + 256] = 0;
    __syncthreads();
    for (int e = beg + t; e < end; e += 256)
        atomicAdd(&lcnt[packed[e] & (BNODES - 1)], 1);
    __syncthreads();

    const int v0 = lcnt[2 * t], v1 = lcnt[2 * t + 1];
    pair[t] = v0 + v1;
    __syncthreads();
    for (int off = 1; off < 256; off <<= 1) {
        const int u = (t >= off) ? pair[t - off] : 0;
        __syncthreads();
        pair[t] += u;
        __syncthreads();
    }
    const int pexcl = pair[t] - (v0 + v1);
    __syncthreads();
    lcnt[2 * t]     = pexcl;
    lcnt[2 * t + 1] = pexcl + v0;
    __syncthreads();

    {
        const int l0 = 2 * t, l1 = 2 * t + 1;
        const int n0 = b * BNODES + l0, n1 = b * BNODES + l1;
        if (n0 <= N_NODES) row_start[n0] = beg + lcnt[l0];
        if (n1 <= N_NODES) row_start[n1] = beg + lcnt[l1];
        lcnt[l0] += beg;
        lcnt[l1] += beg;
    }
    __syncthreads();
    for (int e = beg + t; e < end; e += 256) {
        const unsigned p = packed[e];
        const int pos = atomicAdd(&lcnt[p & (BNODES - 1)], 1);
        esrc[pos] = (int)(p >> BSH);
    }
}

// ---------------- helpers ----------------------------------------------------

__device__ __forceinline__ float uasf(unsigned u) { return __uint_as_float(u); }
__device__ __forceinline__ unsigned f2bf(float f) {
    __hip_bfloat16 b = __float2bfloat16(f);
    return (unsigned)*reinterpret_cast<unsigned short*>(&b);
}

// ---------------- W concat to bf16: Wcat[m][j][k<64:rel, k>=64:root] --------

__global__ __launch_bounds__(256) void wcat_kernel(
    const float* __restrict__ Wrel1, const float* __restrict__ Wroot1,
    const float* __restrict__ Wrel2, const float* __restrict__ Wroot2,
    unsigned short* __restrict__ Wcat)
{
    const float* Wrel  = blockIdx.x ? Wrel2 : Wrel1;
    const float* Wroot = blockIdx.x ? Wroot2 : Wroot1;
    unsigned short* O = Wcat + blockIdx.x * 64 * 128;
    for (int i = threadIdx.x; i < 4096; i += 256) {
        const int j = i >> 6, k = i & 63;
        O[j * 128 + k]      = (unsigned short)f2bf(Wrel[i]);
        O[j * 128 + 64 + k] = (unsigned short)f2bf(Wroot[i]);
    }
}

// ---------------- x -> bf16 copy --------------------------------------------

__global__ __launch_bounds__(256) void tobf_kernel(
    const float* __restrict__ in, unsigned short* __restrict__ out, int n8)
{
    const int i = blockIdx.x * 256 + threadIdx.x;
    if (i >= n8) return;
    const float4 v0 = *reinterpret_cast<const float4*>(&in[(long)i * 8]);
    const float4 v1 = *reinterpret_cast<const float4*>(&in[(long)i * 8 + 4]);
    uint4 o;
    o.x = f2bf(v0.x) | (f2bf(v0.y) << 16);
    o.y = f2bf(v0.z) | (f2bf(v0.w) << 16);
    o.z = f2bf(v1.x) | (f2bf(v1.y) << 16);
    o.w = f2bf(v1.z) | (f2bf(v1.w) << 16);
    *reinterpret_cast<uint4*>(&out[(long)i * 8]) = o;
}

// ---------------- gather (bf16 rows): agg[i] = sum_{j->i} xin[j] ------------

__global__ __launch_bounds__(256) void gather_bf(
    const unsigned short* __restrict__ xin,
    const int* __restrict__ row_start,
    const int* __restrict__ esrc,
    unsigned short* __restrict__ agg)
{
    const int wid = (blockIdx.x * 256 + threadIdx.x) >> 6;
    if (wid >= N_NODES) return;
    const int lane = threadIdx.x & 63;
    const int g = lane >> 3;      // 0..7 edge slot
    const int c = lane & 7;       // 0..7 16B chunk

    const int beg = row_start[wid];
    const int end = row_start[wid + 1];

    float a0 = 0.f, a1 = 0.f, a2 = 0.f, a3 = 0.f,
          a4 = 0.f, a5 = 0.f, a6 = 0.f, a7 = 0.f;
    for (int e = beg; e < end; e += 16) {
        const int i0 = e + g;
        const int i1 = e + 8 + g;
        if (i0 < end) {
            const uint4 u = *reinterpret_cast<const uint4*>(
                &xin[(long)esrc[i0] * D + c * 8]);
            a0 += uasf(u.x << 16); a1 += uasf(u.x & 0xFFFF0000u);
            a2 += uasf(u.y << 16); a3 += uasf(u.y & 0xFFFF0000u);
            a4 += uasf(u.z << 16); a5 += uasf(u.z & 0xFFFF0000u);
            a6 += uasf(u.w << 16); a7 += uasf(u.w & 0xFFFF0000u);
        }
        if (i1 < end) {
            const uint4 u = *reinterpret_cast<const uint4*>(
                &xin[(long)esrc[i1] * D + c * 8]);
            a0 += uasf(u.x << 16); a1 += uasf(u.x & 0xFFFF0000u);
            a2 += uasf(u.y << 16); a3 += uasf(u.y & 0xFFFF0000u);
            a4 += uasf(u.z << 16); a5 += uasf(u.z & 0xFFFF0000u);
            a6 += uasf(u.w << 16); a7 += uasf(u.w & 0xFFFF0000u);
        }
    }
#pragma unroll
    for (int m = 8; m <= 32; m <<= 1) {
        a0 += __shfl_xor(a0, m); a1 += __shfl_xor(a1, m);
        a2 += __shfl_xor(a2, m); a3 += __shfl_xor(a3, m);
        a4 += __shfl_xor(a4, m); a5 += __shfl_xor(a5, m);
        a6 += __shfl_xor(a6, m); a7 += __shfl_xor(a7, m);
    }
    if (g == 0) {
        uint4 o;
        o.x = f2bf(a0) | (f2bf(a1) << 16);
        o.y = f2bf(a2) | (f2bf(a3) << 16);
        o.z = f2bf(a4) | (f2bf(a5) << 16);
        o.w = f2bf(a6) | (f2bf(a7) << 16);
        *reinterpret_cast<uint4*>(&agg[(long)wid * D + c * 8]) = o;
    }
}

// ---------------- dense via MFMA: out = [relu]([agg|x] @ Wcat^T + b) --------
// Block = 64 nodes, 4 waves; wave = 16 nodes x 64 cols, K=128.
// mfma_f32_16x16x32_bf16: A lane(l) = A[l&15][(l>>4)*8+j]; B lane(l) =
// B[(l>>4)*8+j][l&15] (we feed W[col][k] -> B = W^T -> D = A.W^T);
// D: col=lane&15, row=(lane>>4)*4+reg  [learn_hip m89].
// LDS rows padded to 136 bf16 (272 B) -> conflict-free b128 reads.
#define LSTR 136
template <typename OT, int RELU>
__global__ __launch_bounds__(256, 4) void dense_mfma(
    const unsigned short* __restrict__ agg,   // [N][64] bf16
    const unsigned short* __restrict__ xin,   // [N][64] bf16
    const unsigned short* __restrict__ Wcat,  // [64][128] bf16
    const float* __restrict__ brel,
    OT* __restrict__ out)
{
    __shared__ __align__(16) short Wl[64 * LSTR];
    __shared__ __align__(16) short Al[64 * LSTR];

    const int t = threadIdx.x;
    const int node0 = blockIdx.x * 64;

    // stage W: 64 rows x 16 chunks of 16B
    for (int i = t; i < 1024; i += 256) {
        const int j = i >> 4, c = i & 15;
        *reinterpret_cast<uint4*>(&Wl[j * LSTR + c * 8]) =
            *reinterpret_cast<const uint4*>(&Wcat[j * 128 + c * 8]);
    }
    // stage A: rows = nodes; k<64 from agg, k>=64 from xin
    for (int i = t; i < 1024; i += 256) {
        const int n = i >> 4, c = i & 15;
        int gn = node0 + n; if (gn > N_NODES - 1) gn = N_NODES - 1;
        const uint4 v = (c < 8)
            ? *reinterpret_cast<const uint4*>(&agg[(long)gn * D + c * 8])
            : *reinterpret_cast<const uint4*>(&xin[(long)gn * D + (c - 8) * 8]);
        *reinterpret_cast<uint4*>(&Al[n * LSTR + c * 8]) = v;
    }
    __syncthreads();

    const int lane = t & 63;
    const int w = t >> 6;          // wave id: nodes w*16..w*16+15
    const int lr = lane & 15;      // A row / B col within 16
    const int q = lane >> 4;       // k-chunk selector

    // A fragments for this wave's 16 rows, 4 k-steps
    bf16x8 afrag[4];
#pragma unroll
    for (int kk = 0; kk < 4; ++kk)
        afrag[kk] = *reinterpret_cast<const bf16x8*>(
            &Al[(w * 16 + lr) * LSTR + kk * 32 + q * 8]);

    f32x4 acc[4] = {{0.f,0.f,0.f,0.f},{0.f,0.f,0.f,0.f},
                    {0.f,0.f,0.f,0.f},{0.f,0.f,0.f,0.f}};
#pragma unroll
    for (int f = 0; f < 4; ++f) {
#pragma unroll
        for (int kk = 0; kk < 4; ++kk) {
            const bf16x8 bfrag = *reinterpret_cast<const bf16x8*>(
                &Wl[(f * 16 + lr) * LSTR + kk * 32 + q * 8]);
            acc[f] = __builtin_amdgcn_mfma_f32_16x16x32_bf16(
                afrag[kk], bfrag, acc[f], 0, 0, 0);
        }
    }

#pragma unroll
    for (int f = 0; f < 4; ++f) {
        const int col = f * 16 + lr;
        const float bias = brel[col];
#pragma unroll
        for (int r = 0; r < 4; ++r) {
            const int node = node0 + w * 16 + q * 4 + r;
            if (node < N_NODES) {
                float v = acc[f][r] + bias;
                if (RELU) v = fmaxf(v, 0.f);
                if constexpr (sizeof(OT) == 4)
                    ((float*)out)[(long)node * D + col] = v;
                else
                    ((unsigned short*)out)[(long)node * D + col] =
                        (unsigned short)f2bf(v);
            }
        }
    }
}

// ---------------------------------------------------------------------------

extern "C" void kernel_launch(void* const* d_in, const int* in_sizes, int n_in,
                              void* d_out, int out_size, void* d_ws, size_t ws_size,
                              hipStream_t stream)
{
    const float* x     = (const float*)d_in[0];
    const int*   ei    = (const int*)d_in[1];
    const float* Wrel1 = (const float*)d_in[2];
    const float* brel1 = (const float*)d_in[3];
    const float* Wroot1= (const float*)d_in[4];
    const float* Wrel2 = (const float*)d_in[5];
    const float* brel2 = (const float*)d_in[6];
    const float* Wroot2= (const float*)d_in[7];
    float* out = (float*)d_out;

    const int n_edges = in_sizes[1] / 2;
    const int* src = ei;
    const int* dst = ei + n_edges;

    // workspace layout (int units)
    int* base      = (int*)d_ws;
    int* row_start = base;                        // 100352 (padded)
    int* bstart    = base + 100352;               // 320
    int* bcursor   = base + 100672;               // 256
    int* bcount    = base + 100928;               // 256
    unsigned short* Wcat = (unsigned short*)(base + 101184);
    // Wcat = 2 matrices x 64x128 bf16 = 16384 bf16 = 32768 B = 8192 ints
    int* esrc      = base + 109376;               // 101184 + 8192 (FIX: was 105280, overlapped Wcat)
    const size_t xbf_off = (((size_t)(109376 + n_edges) * 4) + 255) & ~(size_t)255;
    const size_t row_bf  = (size_t)N_NODES * D * 2;     // 12.8 MB
    const size_t agg_off = xbf_off + row_bf;
    const size_t h_off   = agg_off + row_bf;

    unsigned short* xbf = (unsigned short*)((char*)d_ws + xbf_off);
    unsigned short* agg = (unsigned short*)((char*)d_ws + agg_off);
    unsigned short* h   = (unsigned short*)((char*)d_ws + h_off);
    unsigned* packed    = (unsigned*)agg;   // consumed by bucket_csr before gather1

    const int BB = (n_edges + EPB - 1) / EPB;
    hipMemsetAsync(bcount, 0, NBUCK * sizeof(int), stream);
    bucket_count<<<BB, 256, 0, stream>>>(dst, bcount, n_edges);
    bucket_scan<<<1, 256, 0, stream>>>(bcount, bstart, bcursor);
    wcat_kernel<<<2, 256, 0, stream>>>(Wrel1, Wroot1, Wrel2, Wroot2, Wcat);
    tobf_kernel<<<(N_NODES * D / 8 + 255) / 256, 256, 0, stream>>>(x, xbf, N_NODES * D / 8);
    bucket_scatter<<<BB, 256, 0, stream>>>(src, dst, bcursor, packed, n_edges);
    bucket_csr<<<NBUCK, 256, 0, stream>>>(packed, bstart, row_start, esrc);

    const int GB = (N_NODES * 64 + 255) / 256;   // gather: wave per node
    const int DB = (N_NODES + 63) / 64;          // dense: 64 nodes per block

    // layer 1: h = relu([agg|x] @ Wcat1^T + b1)   (bf16 out)
    gather_bf<<<GB, 256, 0, stream>>>(xbf, row_start, esrc, agg);
    dense_mfma<__hip_bfloat16, 1><<<DB, 256, 0, stream>>>(
        agg, xbf, Wcat, brel1, (__hip_bfloat16*)h);
    // layer 2: out = [agg|h] @ Wcat2^T + b2       (f32 out)
    gather_bf<<<GB, 256, 0, stream>>>(h, row_start, esrc, agg);
    dense_mfma<float, 0><<<DB, 256, 0, stream>>>(
        agg, h, Wcat + 64 * 128, brel2, out);
}